// Round 1
// baseline (1430.339 us; speedup 1.0000x reference)
//
#include <hip/hip_runtime.h>
#include <stdint.h>

#define D_DIM 1024
#define M_TOT 16384   // 8 * 2048
#define N_LAYERS 3

typedef unsigned short u16;
typedef __attribute__((ext_vector_type(8))) short bf16x8;   // MFMA A/B frag: 8 bf16 = 4 VGPR
typedef __attribute__((ext_vector_type(4))) float f32x4;    // MFMA C/D frag
typedef __attribute__((ext_vector_type(4))) unsigned short u16x4;

typedef __attribute__((address_space(1))) void gvoid_t;
typedef __attribute__((address_space(3))) void lvoid_t;

__device__ __forceinline__ float b2f(u16 u) {
  union { unsigned int i; float f; } x; x.i = ((unsigned int)u) << 16; return x.f;
}
__device__ __forceinline__ u16 f2b(float f) {  // round-to-nearest-even f32 -> bf16
  union { float f; unsigned int i; } x; x.f = f;
  unsigned int r = x.i + 0x7fffu + ((x.i >> 16) & 1u);
  return (u16)(r >> 16);
}

// async global->LDS, 16B per lane. LDS dest = wave-uniform base + lane*16 (HW rule).
__device__ __forceinline__ void gload_lds16(const void* g, void* l) {
  __builtin_amdgcn_global_load_lds((gvoid_t*)(uintptr_t)g,
                                   (lvoid_t*)(unsigned int)(uintptr_t)l, 16, 0, 0);
}

// Stage a 128x64 bf16 tile (rows row0.., cols k0..k0+63, ld=1024) into LDS [128][64] row-major.
// 256 threads * 16B * 4 chunks = 16 KB. linear LDS off = t*16 + c*4096  -> row=t/8+c*32, col=(t%8)*8
__device__ __forceinline__ void stage128x64(const u16* __restrict__ g, int row0, int k0,
                                            u16* lds, int t) {
  int w = t >> 6;
  const u16* gp = g + (size_t)(row0 + (t >> 3)) * D_DIM + k0 + (t & 7) * 8;
  char* lb = (char*)lds + w * 1024;
  gload_lds16(gp,                  lb);
  gload_lds16(gp + 32 * D_DIM,     lb + 4096);
  gload_lds16(gp + 64 * D_DIM,     lb + 8192);
  gload_lds16(gp + 96 * D_DIM,     lb + 12288);
}

// One BK=64 compute step: 2 k-slices x 4x4 fragment MFMAs per wave (wave tile 64x64).
__device__ __forceinline__ void mfma_step(const u16* As, const u16* Bs, int wm, int wn, int l,
                                          f32x4 (&acc)[4][4]) {
  int lm = l & 15, lk = (l >> 4) * 8;
  const u16* Ab = As + (wm * 64 + lm) * 64 + lk;
  const u16* Bb = Bs + (wn * 64 + lm) * 64 + lk;
#pragma unroll
  for (int ks = 0; ks < 2; ks++) {
    bf16x8 av[4], bv[4];
#pragma unroll
    for (int mi = 0; mi < 4; mi++) av[mi] = *(const bf16x8*)(Ab + mi * 1024 + ks * 32);
#pragma unroll
    for (int ni = 0; ni < 4; ni++) bv[ni] = *(const bf16x8*)(Bb + ni * 1024 + ks * 32);
#pragma unroll
    for (int mi = 0; mi < 4; mi++)
#pragma unroll
      for (int ni = 0; ni < 4; ni++)
        acc[mi][ni] = __builtin_amdgcn_mfma_f32_16x16x32_bf16(av[mi], bv[ni], acc[mi][ni], 0, 0, 0);
  }
}

// Full K=1024 loop (m97 structure: stage -> barrier -> compute -> barrier).
__device__ __forceinline__ void gemm_k(const u16* __restrict__ A, const u16* __restrict__ B,
                                       int bm0, int bn0, u16* As, u16* Bs, int t,
                                       f32x4 (&acc)[4][4]) {
  int w = t >> 6, l = t & 63, wm = w >> 1, wn = w & 1;
  for (int kt = 0; kt < 16; kt++) {
    stage128x64(A, bm0, kt * 64, As, t);
    stage128x64(B, bn0, kt * 64, Bs, t);
    __syncthreads();               // compiler emits s_waitcnt vmcnt(0) before s_barrier
    mfma_step(As, Bs, wm, wn, l, acc);
    __syncthreads();
  }
}

// EPI==0: gate GEMM  -> outB[m,n] = bf16( sigmoid(acc+bin[n]) * xf[m,n] * decay[n] )
// EPI==1: out GEMM   -> outF[m,n] = acc + bout[n] + xf[m,n]          (pre-LN, f32)
template <int EPI>
__global__ __launch_bounds__(256) void gemm_fused(const u16* __restrict__ A, const u16* __restrict__ B,
                                                  const float* __restrict__ bias,
                                                  const float* __restrict__ decay,
                                                  const float* __restrict__ xf,
                                                  u16* __restrict__ outB, float* __restrict__ outF) {
  __shared__ __align__(16) u16 As[8192];
  __shared__ __align__(16) u16 Bs[8192];
  int t = threadIdx.x;
  int bn0 = blockIdx.x * 128, bm0 = blockIdx.y * 128;
  f32x4 acc[4][4];
#pragma unroll
  for (int mi = 0; mi < 4; mi++)
#pragma unroll
    for (int ni = 0; ni < 4; ni++) acc[mi][ni] = 0.0f;

  gemm_k(A, B, bm0, bn0, As, Bs, t, acc);

  int w = t >> 6, l = t & 63, wm = w >> 1, wn = w & 1;
  int lm = l & 15, lr = (l >> 4) * 4;   // C/D layout: col=lane&15, row=(lane>>4)*4+reg  [m89/m91]
  int nidx[4]; float bia[4], dec[4];
#pragma unroll
  for (int ni = 0; ni < 4; ni++) {
    nidx[ni] = bn0 + wn * 64 + ni * 16 + lm;
    bia[ni] = bias[nidx[ni]];
    dec[ni] = (EPI == 0) ? decay[nidx[ni]] : 0.0f;
  }
#pragma unroll
  for (int mi = 0; mi < 4; mi++)
#pragma unroll
    for (int j = 0; j < 4; j++) {
      size_t m = (size_t)bm0 + wm * 64 + mi * 16 + lr + j;
      const float* xr = xf + m * D_DIM;
      if (EPI == 0) {
        u16* orow = outB + m * D_DIM;
#pragma unroll
        for (int ni = 0; ni < 4; ni++) {
          float v = acc[mi][ni][j] + bia[ni];
          float g = 1.0f / (1.0f + __expf(-v));
          orow[nidx[ni]] = f2b(g * xr[nidx[ni]] * dec[ni]);
        }
      } else {
        float* orow = outF + m * D_DIM;
#pragma unroll
        for (int ni = 0; ni < 4; ni++)
          orow[nidx[ni]] = acc[mi][ni][j] + bia[ni] + xr[nidx[ni]];
      }
    }
}

// MoE: pred[m,f] = sum_e p[m,e] * ( z[m,:] . expW[e][f,:] + exp_b[e][f] )
// 4 sequential expert K-loops per block; probs staged in LDS; combined acc in registers.
__global__ __launch_bounds__(256) void moe_kernel(const u16* __restrict__ zb, const u16* __restrict__ wexp,
                                                  const float* __restrict__ expb,
                                                  const float* __restrict__ probs,
                                                  float* __restrict__ pred) {
  __shared__ __align__(16) u16 As[8192];
  __shared__ __align__(16) u16 Bs[8192];
  __shared__ float sP[512];   // [128 rows][4 experts]
  int t = threadIdx.x;
  int bn0 = blockIdx.x * 128, bm0 = blockIdx.y * 128;
  if (t < 128) ((f32x4*)sP)[t] = ((const f32x4*)(probs + (size_t)bm0 * 4))[t];

  int w = t >> 6, l = t & 63, wm = w >> 1, wn = w & 1;
  int lm = l & 15, lr = (l >> 4) * 4;
  f32x4 accC[4][4];
#pragma unroll
  for (int mi = 0; mi < 4; mi++)
#pragma unroll
    for (int ni = 0; ni < 4; ni++) accC[mi][ni] = 0.0f;
  int nidx[4];
#pragma unroll
  for (int ni = 0; ni < 4; ni++) nidx[ni] = bn0 + wn * 64 + ni * 16 + lm;

#pragma unroll 1
  for (int e = 0; e < 4; e++) {
    f32x4 acc[4][4];
#pragma unroll
    for (int mi = 0; mi < 4; mi++)
#pragma unroll
      for (int ni = 0; ni < 4; ni++) acc[mi][ni] = 0.0f;
    gemm_k(zb, wexp + (size_t)e * 1048576, bm0, bn0, As, Bs, t, acc);
    float be[4];
#pragma unroll
    for (int ni = 0; ni < 4; ni++) be[ni] = expb[e * 1024 + nidx[ni]];
#pragma unroll
    for (int mi = 0; mi < 4; mi++)
#pragma unroll
      for (int j = 0; j < 4; j++) {
        int rl = wm * 64 + mi * 16 + lr + j;
        float p = sP[rl * 4 + e];
#pragma unroll
        for (int ni = 0; ni < 4; ni++)
          accC[mi][ni][j] += p * (acc[mi][ni][j] + be[ni]);
      }
  }
#pragma unroll
  for (int mi = 0; mi < 4; mi++)
#pragma unroll
    for (int j = 0; j < 4; j++) {
      size_t m = (size_t)bm0 + wm * 64 + mi * 16 + lr + j;
      float* orow = pred + m * D_DIM;
#pragma unroll
      for (int ni = 0; ni < 4; ni++) orow[nidx[ni]] = accC[mi][ni][j];
    }
}

// Row LayerNorm over D=1024; writes f32 (next residual / final out) + bf16 (next GEMM A).
__global__ __launch_bounds__(256) void ln_kernel(const float* __restrict__ src,
                                                 const float* __restrict__ gamma,
                                                 const float* __restrict__ beta,
                                                 float* __restrict__ dstF, u16* __restrict__ dstB) {
  size_t row = blockIdx.x;
  int t = threadIdx.x, w = t >> 6, l = t & 63;
  f32x4 v = ((const f32x4*)(src + row * D_DIM))[t];
  float s = v[0] + v[1] + v[2] + v[3];
  float q = v[0]*v[0] + v[1]*v[1] + v[2]*v[2] + v[3]*v[3];
#pragma unroll
  for (int off = 32; off; off >>= 1) { s += __shfl_xor(s, off); q += __shfl_xor(q, off); }
  __shared__ float red[8];
  if (l == 0) { red[w] = s; red[4 + w] = q; }
  __syncthreads();
  s = red[0] + red[1] + red[2] + red[3];
  q = red[4] + red[5] + red[6] + red[7];
  float mu = s * (1.0f / 1024.0f);
  float var = q * (1.0f / 1024.0f) - mu * mu;
  float inv = rsqrtf(var + 1e-5f);
  f32x4 g = ((const f32x4*)gamma)[t], b = ((const f32x4*)beta)[t];
  f32x4 y; u16x4 yb;
#pragma unroll
  for (int i = 0; i < 4; i++) { y[i] = (v[i] - mu) * inv * g[i] + b[i]; yb[i] = f2b(y[i]); }
  ((f32x4*)(dstF + row * D_DIM))[t] = y;
  ((u16x4*)(dstB + row * D_DIM))[t] = yb;
}

// f32 -> bf16 elementwise (weights + activations)
__global__ void conv_kernel(const float* __restrict__ src, u16* __restrict__ dst, int n4) {
  int i = blockIdx.x * 256 + threadIdx.x;
  if (i >= n4) return;
  f32x4 v = ((const f32x4*)src)[i];
  u16x4 o;
#pragma unroll
  for (int j = 0; j < 4; j++) o[j] = f2b(v[j]);
  ((u16x4*)dst)[i] = o;
}

// Gate: logits[m,e] = z[m,:] . gW[e,:] + gb[e]; softmax -> probs[m,0..3]. One wave per row.
__global__ __launch_bounds__(256) void gate_kernel(const u16* __restrict__ zb,
                                                   const float* __restrict__ gW,
                                                   const float* __restrict__ gb,
                                                   float* __restrict__ probs) {
  __shared__ float sW[4096];
  int t = threadIdx.x;
#pragma unroll
  for (int c = 0; c < 4; c++) ((f32x4*)sW)[c * 256 + t] = ((const f32x4*)gW)[c * 256 + t];
  __syncthreads();
  int w = t >> 6, l = t & 63;
  size_t m = (size_t)blockIdx.x * 4 + w;
  const u16* zr = zb + m * D_DIM;
  float d0 = 0, d1 = 0, d2 = 0, d3 = 0;
#pragma unroll
  for (int c = 0; c < 4; c++) {
    int k = l * 4 + c * 256;
    u16x4 zv = *(const u16x4*)(zr + k);
    f32x4 w0 = *(const f32x4*)&sW[k];
    f32x4 w1 = *(const f32x4*)&sW[1024 + k];
    f32x4 w2 = *(const f32x4*)&sW[2048 + k];
    f32x4 w3 = *(const f32x4*)&sW[3072 + k];
#pragma unroll
    for (int i = 0; i < 4; i++) {
      float zf = b2f(zv[i]);
      d0 += zf * w0[i]; d1 += zf * w1[i]; d2 += zf * w2[i]; d3 += zf * w3[i];
    }
  }
#pragma unroll
  for (int off = 32; off; off >>= 1) {
    d0 += __shfl_xor(d0, off); d1 += __shfl_xor(d1, off);
    d2 += __shfl_xor(d2, off); d3 += __shfl_xor(d3, off);
  }
  if (l == 0) {
    float l0 = d0 + gb[0], l1 = d1 + gb[1], l2 = d2 + gb[2], l3 = d3 + gb[3];
    float mx = fmaxf(fmaxf(l0, l1), fmaxf(l2, l3));
    float e0 = __expf(l0 - mx), e1 = __expf(l1 - mx), e2 = __expf(l2 - mx), e3 = __expf(l3 - mx);
    float inv = 1.0f / (e0 + e1 + e2 + e3);
    f32x4 r; r[0] = e0 * inv; r[1] = e1 * inv; r[2] = e2 * inv; r[3] = e3 * inv;
    ((f32x4*)(probs + m * 4))[0] = r;
  }
}

extern "C" void kernel_launch(void* const* d_in, const int* in_sizes, int n_in,
                              void* d_out, int out_size, void* d_ws, size_t ws_size,
                              hipStream_t stream) {
  (void)in_sizes; (void)n_in; (void)out_size; (void)ws_size;
  const float* x_ctx    = (const float*)d_in[0];
  const float* x_tgt    = (const float*)d_in[1];
  const float* enc_Win  = (const float*)d_in[2];
  const float* enc_bin  = (const float*)d_in[3];
  const float* enc_dec  = (const float*)d_in[4];
  const float* enc_Wout = (const float*)d_in[5];
  const float* enc_bout = (const float*)d_in[6];
  const float* enc_gam  = (const float*)d_in[7];
  const float* enc_bet  = (const float*)d_in[8];
  const float* tgt_Win  = (const float*)d_in[9];
  const float* tgt_bin  = (const float*)d_in[10];
  const float* tgt_dec  = (const float*)d_in[11];
  const float* tgt_Wout = (const float*)d_in[12];
  const float* tgt_bout = (const float*)d_in[13];
  const float* tgt_gam  = (const float*)d_in[14];
  const float* tgt_bet  = (const float*)d_in[15];
  const float* gate_W   = (const float*)d_in[16];
  const float* gate_b   = (const float*)d_in[17];
  const float* exp_W    = (const float*)d_in[18];
  const float* exp_b    = (const float*)d_in[19];

  // d_out layout: pred_z[16M] | gate_probs[64K] | z_target[16M]
  float* out_pred  = (float*)d_out;
  float* out_probs = out_pred + (size_t)M_TOT * D_DIM;
  float* out_ztgt  = out_probs + (size_t)M_TOT * 4;

  // ws: weights(bf16, 32MB) | xb(32MB) | sb(32MB) | F1(64MB).  pred_z slot doubles as F0 (pre-LN).
  char* ws = (char*)d_ws;
  u16* wbEncIn  = (u16*)ws;
  u16* wbEncOut = wbEncIn  + (size_t)3 * 1048576;
  u16* wbTgtIn  = wbEncOut + (size_t)3 * 1048576;
  u16* wbTgtOut = wbTgtIn  + (size_t)3 * 1048576;
  u16* wbExp    = wbTgtOut + (size_t)3 * 1048576;
  u16* xb       = wbExp    + (size_t)4 * 1048576;
  u16* sb       = xb + (size_t)M_TOT * D_DIM;
  float* F1     = (float*)(sb + (size_t)M_TOT * D_DIM);
  float* F0     = out_pred;   // scratch until MoE writes final pred_z

  dim3 gg(8, 128);

  auto conv = [&](const float* s, u16* d, size_t n) {
    int n4 = (int)(n / 4);
    conv_kernel<<<(n4 + 255) / 256, 256, 0, stream>>>(s, d, n4);
  };
  conv(enc_Win,  wbEncIn,  (size_t)3 * 1048576);
  conv(enc_Wout, wbEncOut, (size_t)3 * 1048576);
  conv(tgt_Win,  wbTgtIn,  (size_t)3 * 1048576);
  conv(tgt_Wout, wbTgtOut, (size_t)3 * 1048576);
  conv(exp_W,    wbExp,    (size_t)4 * 1048576);

  // ---- target stack first (frees F0 = pred_z slot for MoE at the end) ----
  conv(x_tgt, xb, (size_t)M_TOT * D_DIM);
  const float* xf = x_tgt;
  for (int i = 0; i < N_LAYERS; i++) {
    gemm_fused<0><<<gg, 256, 0, stream>>>(xb, wbTgtIn + (size_t)i * 1048576,
                                          tgt_bin + i * 1024, tgt_dec + i * 1024, xf, sb, nullptr);
    gemm_fused<1><<<gg, 256, 0, stream>>>(sb, wbTgtOut + (size_t)i * 1048576,
                                          tgt_bout + i * 1024, nullptr, xf, nullptr, F0);
    float* ofp = (i == N_LAYERS - 1) ? out_ztgt : F1;
    ln_kernel<<<M_TOT, 256, 0, stream>>>(F0, tgt_gam + i * 1024, tgt_bet + i * 1024, ofp, xb);
    xf = ofp;
  }

  // ---- context stack ----
  conv(x_ctx, xb, (size_t)M_TOT * D_DIM);
  xf = x_ctx;
  for (int i = 0; i < N_LAYERS; i++) {
    gemm_fused<0><<<gg, 256, 0, stream>>>(xb, wbEncIn + (size_t)i * 1048576,
                                          enc_bin + i * 1024, enc_dec + i * 1024, xf, sb, nullptr);
    gemm_fused<1><<<gg, 256, 0, stream>>>(sb, wbEncOut + (size_t)i * 1048576,
                                          enc_bout + i * 1024, nullptr, xf, nullptr, F0);
    ln_kernel<<<M_TOT, 256, 0, stream>>>(F0, enc_gam + i * 1024, enc_bet + i * 1024, F1, xb);
    xf = F1;
  }

  // ---- MoE head (reads xb = z_context bf16) ----
  gate_kernel<<<M_TOT / 4, 256, 0, stream>>>(xb, gate_W, gate_b, out_probs);
  moe_kernel<<<gg, 256, 0, stream>>>(xb, wbExp, exp_b, out_probs, out_pred);
}

// Round 2
// 979.842 us; speedup vs baseline: 1.4598x; 1.4598x over previous
//
#include <hip/hip_runtime.h>
#include <stdint.h>

#define D_DIM 1024
#define M_TOT 16384   // 8 * 2048
#define N_LAYERS 3
#define NT 16         // K tiles (K=1024 / BK=64)

typedef unsigned short u16;
typedef __attribute__((ext_vector_type(8))) short bf16x8;   // MFMA A/B frag
typedef __attribute__((ext_vector_type(4))) float f32x4;    // MFMA C/D frag
typedef __attribute__((ext_vector_type(4))) unsigned short u16x4;

typedef __attribute__((address_space(1))) void gvoid_t;
typedef __attribute__((address_space(3))) void lvoid_t;

#define CFENCE() asm volatile("" ::: "memory")

__device__ __forceinline__ float b2f(u16 u) {
  union { unsigned int i; float f; } x; x.i = ((unsigned int)u) << 16; return x.f;
}
__device__ __forceinline__ u16 f2b(float f) {  // RNE f32 -> bf16
  union { float f; unsigned int i; } x; x.f = f;
  unsigned int r = x.i + 0x7fffu + ((x.i >> 16) & 1u);
  return (u16)(r >> 16);
}

__device__ __forceinline__ void gload_lds16(const void* g, void* l) {
  __builtin_amdgcn_global_load_lds((gvoid_t*)(uintptr_t)g,
                                   (lvoid_t*)(unsigned int)(uintptr_t)l, 16, 0, 0);
}

// ---------------------------------------------------------------------------
// 8-phase 256x256 GEMM engine (T2 swizzle + T3/T4 counted vmcnt + T5 setprio)
// A [M x 1024] bf16 row-major, B [N x 1024] bf16 row-major (B^T GEMM).
// EPI 0: outB = bf16(sigmoid(acc+bias)*xf*decay)     (gate GEMM)
// EPI 1: outF = acc + bias + xf                      (pre-LN, f32)
// EPI 2: outF = (eIdx? outF:0) + probs[m,eIdx]*(acc+bias)   (MoE pass, RMW)
// ---------------------------------------------------------------------------
template <int EPI>
__global__ __launch_bounds__(512) void gemm8p(
    const u16* __restrict__ A, const u16* __restrict__ Bm,
    const float* __restrict__ bias, const float* __restrict__ decay,
    const float* __restrict__ xf, const float* __restrict__ probs, int eIdx,
    u16* __restrict__ outB, float* __restrict__ outF)
{
  // 128 KB: 2 buffers x { B: 4 chunks x 8KB, A: 4 chunks x 8KB }
  __shared__ __align__(16) u16 lds[65536];
  const char* ldsc = (const char*)lds;

  int t = threadIdx.x;
  int wid = t >> 6, l = t & 63;
  int wm = wid >> 2, wn = wid & 3;      // 2 x 4 waves; wave tile 128 x 64
  int lm = l & 15, g = l >> 4;

  // XCD-chunked swizzle: nwg=256 divisible by 8 -> bijective
  int orig = blockIdx.x;
  int wg = ((orig & 7) << 5) | (orig >> 3);
  int bm0 = (wg >> 2) << 8, bn0 = (wg & 3) << 8;

  // ---- staging source (pre-swizzled global address; LDS dest linear) ----
  int rowL = t >> 3;                                  // 0..63 (row within 64-row chunk)
  int colE = ((t & 7) ^ (rowL & 7)) << 3;             // element col (XOR pre-swizzle)
  const u16* pA = A + (size_t)(bm0 + ((rowL >> 5) << 7) + (rowL & 31)) * D_DIM + colE;
  const u16* pB = Bm + (size_t)(bn0 + rowL) * D_DIM + colE;
  u16* ldsW = lds + wid * 512;                        // wave-uniform dst base (+chunk offs)

  // ---- read-side swizzled col offsets (bytes within 128B row) ----
  int xc0 = (g * 16) ^ ((lm & 7) << 4);
  int xc1 = xc0 ^ 64;

  // LDS dst (u16 units): buf*32768 | B chunk c: c*4096 | A: 16384 + q*4096
#define STAGE_B(tile, c) gload_lds16(pB + (size_t)(tile) * 64 + (size_t)(c) * 65536, \
                                     ldsW + ((tile) & 1) * 32768 + (c) * 4096)
#define STAGE_A(tile, q) gload_lds16(pA + (size_t)(tile) * 64 + (size_t)(q) * 32768, \
                                     ldsW + ((tile) & 1) * 32768 + 16384 + (q) * 4096)
  // frag reads (byte offsets; buffer stride 65536 B)
#define BFRAG(cur, ni, ks) (*(const bf16x8*)(ldsc + (cur) * 65536 + wn * 8192 + \
                            ((ni) * 16 + lm) * 128 + ((ks) ? xc1 : xc0)))
#define AFRAG(cur, q, s, ks) (*(const bf16x8*)(ldsc + (cur) * 65536 + 32768 + (q) * 8192 + \
                              (wm * 32 + (s) * 16 + lm) * 128 + ((ks) ? xc1 : xc0)))

  f32x4 acc[8][4];
#pragma unroll
  for (int mi = 0; mi < 8; mi++)
#pragma unroll
    for (int ni = 0; ni < 4; ni++) acc[mi][ni] = 0.0f;

  // ---- prologue: tile0 fully (8 rounds) + tile1 B0-3,A0,A1 (6 rounds) ----
#pragma unroll
  for (int c = 0; c < 4; c++) STAGE_B(0, c);
#pragma unroll
  for (int q = 0; q < 4; q++) STAGE_A(0, q);
#pragma unroll
  for (int c = 0; c < 4; c++) STAGE_B(1, c);
  STAGE_A(1, 0); STAGE_A(1, 1);

  bf16x8 bf[4][2];
#pragma unroll 2
  for (int tt = 0; tt < NT; ++tt) {
    int cur = tt & 1;
    // ---- phase 0 (tile boundary) ----
    if (tt + 1 < NT) {
      STAGE_A(tt + 1, 2); STAGE_A(tt + 1, 3);     // regions dead since tile tt-1 ph2/3
      asm volatile("s_waitcnt vmcnt(8)" ::: "memory");   // tile tt's 8 rounds landed
    } else {
      asm volatile("s_waitcnt vmcnt(0)" ::: "memory");
    }
    __builtin_amdgcn_s_barrier();
    CFENCE();
    bf16x8 aa[2][2];
#pragma unroll
    for (int ni = 0; ni < 4; ni++) { bf[ni][0] = BFRAG(cur, ni, 0); bf[ni][1] = BFRAG(cur, ni, 1); }
#pragma unroll
    for (int s = 0; s < 2; s++) { aa[s][0] = AFRAG(cur, 0, s, 0); aa[s][1] = AFRAG(cur, 0, s, 1); }
    __builtin_amdgcn_s_setprio(1);
#pragma unroll
    for (int ks = 0; ks < 2; ks++)
#pragma unroll
      for (int s = 0; s < 2; s++)
#pragma unroll
        for (int ni = 0; ni < 4; ni++)
          acc[s][ni] = __builtin_amdgcn_mfma_f32_16x16x32_bf16(aa[s][ks], bf[ni][ks], acc[s][ni], 0, 0, 0);
    __builtin_amdgcn_s_setprio(0);
    CFENCE();
    __builtin_amdgcn_s_barrier();
    CFENCE();
    // ---- phases 1..3 ----
#pragma unroll
    for (int q = 1; q < 4; q++) {
      bf16x8 a2[2][2];
#pragma unroll
      for (int s = 0; s < 2; s++) { a2[s][0] = AFRAG(cur, q, s, 0); a2[s][1] = AFRAG(cur, q, s, 1); }
      if (tt + 2 < NT) {                     // stage tile tt+2 into regions read in phase <= q-1
        if (q == 1)      { STAGE_B(tt + 2, 0); STAGE_B(tt + 2, 1); }
        else if (q == 2) { STAGE_B(tt + 2, 2); STAGE_B(tt + 2, 3); }
        else             { STAGE_A(tt + 2, 0); STAGE_A(tt + 2, 1); }
      }
      __builtin_amdgcn_s_setprio(1);
#pragma unroll
      for (int ks = 0; ks < 2; ks++)
#pragma unroll
        for (int s = 0; s < 2; s++)
#pragma unroll
          for (int ni = 0; ni < 4; ni++)
            acc[2 * q + s][ni] = __builtin_amdgcn_mfma_f32_16x16x32_bf16(a2[s][ks], bf[ni][ks], acc[2 * q + s][ni], 0, 0, 0);
      __builtin_amdgcn_s_setprio(0);
      CFENCE();
      __builtin_amdgcn_s_barrier();
      CFENCE();
    }
  }
#undef STAGE_A
#undef STAGE_B
#undef BFRAG
#undef AFRAG

  // ---- epilogue ----  C layout: m = bm0+wm*128+mi*16+g*4+j, n = bn0+wn*64+ni*16+lm
  int nidx[4]; float bia[4], dec[4];
#pragma unroll
  for (int ni = 0; ni < 4; ni++) {
    nidx[ni] = bn0 + wn * 64 + ni * 16 + lm;
    bia[ni] = bias[nidx[ni]];
    dec[ni] = (EPI == 0) ? decay[nidx[ni]] : 0.0f;
  }
#pragma unroll
  for (int mi = 0; mi < 8; mi++)
#pragma unroll
    for (int j = 0; j < 4; j++) {
      size_t m = (size_t)bm0 + wm * 128 + mi * 16 + g * 4 + j;
      if (EPI == 0) {
        const float* xr = xf + m * D_DIM;
        u16* orow = outB + m * D_DIM;
#pragma unroll
        for (int ni = 0; ni < 4; ni++) {
          float v = acc[mi][ni][j] + bia[ni];
          float gt = 1.0f / (1.0f + __expf(-v));
          orow[nidx[ni]] = f2b(gt * xr[nidx[ni]] * dec[ni]);
        }
      } else if (EPI == 1) {
        const float* xr = xf + m * D_DIM;
        float* orow = outF + m * D_DIM;
#pragma unroll
        for (int ni = 0; ni < 4; ni++)
          orow[nidx[ni]] = acc[mi][ni][j] + bia[ni] + xr[nidx[ni]];
      } else {
        float p = probs[m * 4 + eIdx];
        float* orow = outF + m * D_DIM;
#pragma unroll
        for (int ni = 0; ni < 4; ni++) {
          float v = p * (acc[mi][ni][j] + bia[ni]);
          float prev = eIdx ? orow[nidx[ni]] : 0.0f;
          orow[nidx[ni]] = prev + v;
        }
      }
    }
}

// Row LayerNorm over D=1024; writes f32 + bf16.
__global__ __launch_bounds__(256) void ln_kernel(const float* __restrict__ src,
                                                 const float* __restrict__ gamma,
                                                 const float* __restrict__ beta,
                                                 float* __restrict__ dstF, u16* __restrict__ dstB) {
  size_t row = blockIdx.x;
  int t = threadIdx.x, w = t >> 6, l = t & 63;
  f32x4 v = ((const f32x4*)(src + row * D_DIM))[t];
  float s = v[0] + v[1] + v[2] + v[3];
  float q = v[0]*v[0] + v[1]*v[1] + v[2]*v[2] + v[3]*v[3];
#pragma unroll
  for (int off = 32; off; off >>= 1) { s += __shfl_xor(s, off); q += __shfl_xor(q, off); }
  __shared__ float red[8];
  if (l == 0) { red[w] = s; red[4 + w] = q; }
  __syncthreads();
  s = red[0] + red[1] + red[2] + red[3];
  q = red[4] + red[5] + red[6] + red[7];
  float mu = s * (1.0f / 1024.0f);
  float var = q * (1.0f / 1024.0f) - mu * mu;
  float inv = rsqrtf(var + 1e-5f);
  f32x4 gm = ((const f32x4*)gamma)[t], b = ((const f32x4*)beta)[t];
  f32x4 y; u16x4 yb;
#pragma unroll
  for (int i = 0; i < 4; i++) { y[i] = (v[i] - mu) * inv * gm[i] + b[i]; yb[i] = f2b(y[i]); }
  ((f32x4*)(dstF + row * D_DIM))[t] = y;
  ((u16x4*)(dstB + row * D_DIM))[t] = yb;
}

// f32 -> bf16 elementwise
__global__ void conv_kernel(const float* __restrict__ src, u16* __restrict__ dst, int n4) {
  int i = blockIdx.x * 256 + threadIdx.x;
  if (i >= n4) return;
  f32x4 v = ((const f32x4*)src)[i];
  u16x4 o;
#pragma unroll
  for (int j = 0; j < 4; j++) o[j] = f2b(v[j]);
  ((u16x4*)dst)[i] = o;
}

// Gate: logits + softmax -> probs[m,0..3]. One wave per row.
__global__ __launch_bounds__(256) void gate_kernel(const u16* __restrict__ zb,
                                                   const float* __restrict__ gW,
                                                   const float* __restrict__ gb,
                                                   float* __restrict__ probs) {
  __shared__ float sW[4096];
  int t = threadIdx.x;
#pragma unroll
  for (int c = 0; c < 4; c++) ((f32x4*)sW)[c * 256 + t] = ((const f32x4*)gW)[c * 256 + t];
  __syncthreads();
  int w = t >> 6, l = t & 63;
  size_t m = (size_t)blockIdx.x * 4 + w;
  const u16* zr = zb + m * D_DIM;
  float d0 = 0, d1 = 0, d2 = 0, d3 = 0;
#pragma unroll
  for (int c = 0; c < 4; c++) {
    int k = l * 4 + c * 256;
    u16x4 zv = *(const u16x4*)(zr + k);
    f32x4 w0 = *(const f32x4*)&sW[k];
    f32x4 w1 = *(const f32x4*)&sW[1024 + k];
    f32x4 w2 = *(const f32x4*)&sW[2048 + k];
    f32x4 w3 = *(const f32x4*)&sW[3072 + k];
#pragma unroll
    for (int i = 0; i < 4; i++) {
      float zf = b2f(zv[i]);
      d0 += zf * w0[i]; d1 += zf * w1[i]; d2 += zf * w2[i]; d3 += zf * w3[i];
    }
  }
#pragma unroll
  for (int off = 32; off; off >>= 1) {
    d0 += __shfl_xor(d0, off); d1 += __shfl_xor(d1, off);
    d2 += __shfl_xor(d2, off); d3 += __shfl_xor(d3, off);
  }
  if (l == 0) {
    float l0 = d0 + gb[0], l1 = d1 + gb[1], l2 = d2 + gb[2], l3 = d3 + gb[3];
    float mx = fmaxf(fmaxf(l0, l1), fmaxf(l2, l3));
    float e0 = __expf(l0 - mx), e1 = __expf(l1 - mx), e2 = __expf(l2 - mx), e3 = __expf(l3 - mx);
    float inv = 1.0f / (e0 + e1 + e2 + e3);
    f32x4 r; r[0] = e0 * inv; r[1] = e1 * inv; r[2] = e2 * inv; r[3] = e3 * inv;
    ((f32x4*)(probs + m * 4))[0] = r;
  }
}

extern "C" void kernel_launch(void* const* d_in, const int* in_sizes, int n_in,
                              void* d_out, int out_size, void* d_ws, size_t ws_size,
                              hipStream_t stream) {
  (void)in_sizes; (void)n_in; (void)out_size; (void)ws_size;
  const float* x_ctx    = (const float*)d_in[0];
  const float* x_tgt    = (const float*)d_in[1];
  const float* enc_Win  = (const float*)d_in[2];
  const float* enc_bin  = (const float*)d_in[3];
  const float* enc_dec  = (const float*)d_in[4];
  const float* enc_Wout = (const float*)d_in[5];
  const float* enc_bout = (const float*)d_in[6];
  const float* enc_gam  = (const float*)d_in[7];
  const float* enc_bet  = (const float*)d_in[8];
  const float* tgt_Win  = (const float*)d_in[9];
  const float* tgt_bin  = (const float*)d_in[10];
  const float* tgt_dec  = (const float*)d_in[11];
  const float* tgt_Wout = (const float*)d_in[12];
  const float* tgt_bout = (const float*)d_in[13];
  const float* tgt_gam  = (const float*)d_in[14];
  const float* tgt_bet  = (const float*)d_in[15];
  const float* gate_W   = (const float*)d_in[16];
  const float* gate_b   = (const float*)d_in[17];
  const float* exp_W    = (const float*)d_in[18];
  const float* exp_b    = (const float*)d_in[19];

  // d_out: pred_z[16M] | gate_probs[64K] | z_target[16M]
  float* out_pred  = (float*)d_out;
  float* out_probs = out_pred + (size_t)M_TOT * D_DIM;
  float* out_ztgt  = out_probs + (size_t)M_TOT * 4;

  // ws: bf16 weights (32MB) | xb(32MB) | sb(32MB) | F1(64MB). F0 = out_pred (scratch until MoE).
  char* ws = (char*)d_ws;
  u16* wbEncIn  = (u16*)ws;
  u16* wbEncOut = wbEncIn  + (size_t)3 * 1048576;
  u16* wbTgtIn  = wbEncOut + (size_t)3 * 1048576;
  u16* wbTgtOut = wbTgtIn  + (size_t)3 * 1048576;
  u16* wbExp    = wbTgtOut + (size_t)3 * 1048576;
  u16* xb       = wbExp    + (size_t)4 * 1048576;
  u16* sb       = xb + (size_t)M_TOT * D_DIM;
  float* F1     = (float*)(sb + (size_t)M_TOT * D_DIM);
  float* F0     = out_pred;

  auto conv = [&](const float* s, u16* d, size_t n) {
    int n4 = (int)(n / 4);
    conv_kernel<<<(n4 + 255) / 256, 256, 0, stream>>>(s, d, n4);
  };
  conv(enc_Win,  wbEncIn,  (size_t)3 * 1048576);
  conv(enc_Wout, wbEncOut, (size_t)3 * 1048576);
  conv(tgt_Win,  wbTgtIn,  (size_t)3 * 1048576);
  conv(tgt_Wout, wbTgtOut, (size_t)3 * 1048576);
  conv(exp_W,    wbExp,    (size_t)4 * 1048576);

  // ---- target stack ----
  conv(x_tgt, xb, (size_t)M_TOT * D_DIM);
  const float* xf = x_tgt;
  for (int i = 0; i < N_LAYERS; i++) {
    gemm8p<0><<<256, 512, 0, stream>>>(xb, wbTgtIn + (size_t)i * 1048576,
                                       tgt_bin + i * 1024, tgt_dec + i * 1024, xf,
                                       nullptr, 0, sb, nullptr);
    gemm8p<1><<<256, 512, 0, stream>>>(sb, wbTgtOut + (size_t)i * 1048576,
                                       tgt_bout + i * 1024, nullptr, xf,
                                       nullptr, 0, nullptr, F0);
    float* ofp = (i == N_LAYERS - 1) ? out_ztgt : F1;
    ln_kernel<<<M_TOT, 256, 0, stream>>>(F0, tgt_gam + i * 1024, tgt_bet + i * 1024, ofp, xb);
    xf = ofp;
  }

  // ---- context stack ----
  conv(x_ctx, xb, (size_t)M_TOT * D_DIM);
  xf = x_ctx;
  for (int i = 0; i < N_LAYERS; i++) {
    gemm8p<0><<<256, 512, 0, stream>>>(xb, wbEncIn + (size_t)i * 1048576,
                                       enc_bin + i * 1024, enc_dec + i * 1024, xf,
                                       nullptr, 0, sb, nullptr);
    gemm8p<1><<<256, 512, 0, stream>>>(sb, wbEncOut + (size_t)i * 1048576,
                                       enc_bout + i * 1024, nullptr, xf,
                                       nullptr, 0, nullptr, F0);
    ln_kernel<<<M_TOT, 256, 0, stream>>>(F0, enc_gam + i * 1024, enc_bet + i * 1024, F1, xb);
    xf = F1;
  }

  // ---- MoE head: gate probs, then 4 accumulate passes into pred ----
  gate_kernel<<<M_TOT / 4, 256, 0, stream>>>(xb, gate_W, gate_b, out_probs);
  for (int e = 0; e < 4; e++) {
    gemm8p<2><<<256, 512, 0, stream>>>(xb, wbExp + (size_t)e * 1048576,
                                       exp_b + e * 1024, nullptr, nullptr,
                                       out_probs, e, nullptr, out_pred);
  }
}

// Round 3
// 880.478 us; speedup vs baseline: 1.6245x; 1.1129x over previous
//
#include <hip/hip_runtime.h>
#include <stdint.h>

#define D_DIM 1024
#define M_TOT 16384   // 8 * 2048
#define N_LAYERS 3
#define NT 16         // K tiles (K=1024 / BK=64)

typedef unsigned short u16;
typedef __attribute__((ext_vector_type(8))) short bf16x8;
typedef __attribute__((ext_vector_type(4))) float f32x4;
typedef __attribute__((ext_vector_type(4))) unsigned short u16x4;

typedef __attribute__((address_space(1))) void gvoid_t;
typedef __attribute__((address_space(3))) void lvoid_t;

__device__ __forceinline__ float b2f(u16 u) {
  union { unsigned int i; float f; } x; x.i = ((unsigned int)u) << 16; return x.f;
}
__device__ __forceinline__ u16 f2b(float f) {  // RNE f32 -> bf16
  union { float f; unsigned int i; } x; x.f = f;
  unsigned int r = x.i + 0x7fffu + ((x.i >> 16) & 1u);
  return (u16)(r >> 16);
}

__device__ __forceinline__ void gload_lds16(const void* g, void* l) {
  __builtin_amdgcn_global_load_lds((gvoid_t*)(uintptr_t)g,
                                   (lvoid_t*)(unsigned int)(uintptr_t)l, 16, 0, 0);
}

// Opaque LDS read: compiler's waitcnt pass sees no LDS read -> no vmcnt drain.
// Ordering handled by explicit lgkmcnt(0) + sched_barrier(0) before MFMA (rule #18).
__device__ __forceinline__ bf16x8 dsr128(unsigned addr) {
  bf16x8 r;
  asm volatile("ds_read_b128 %0, %1" : "=v"(r) : "v"(addr));
  return r;
}

// ---------------------------------------------------------------------------
// 8-phase 256x256 GEMM engine. A [M x 1024], B [N x 1024] bf16 row-major (B^T).
// EPI 0: outB = bf16(sigmoid(acc+bias) * xb * decay)
// EPI 1: outB = bf16(acc + bias + xb)                 (pre-LN, bf16)
// EPI 2: outF = (eIdx? outF:0) + probs[m,eIdx]*(acc+bias)   (MoE RMW, f32)
// ---------------------------------------------------------------------------
template <int EPI>
__global__ __launch_bounds__(512) void gemm8p(
    const u16* __restrict__ A, const u16* __restrict__ Bm,
    const float* __restrict__ bias, const float* __restrict__ decay,
    const u16* __restrict__ xfB, const float* __restrict__ probs, int eIdx,
    u16* __restrict__ outB, float* __restrict__ outF)
{
  __shared__ __align__(128) u16 lds[65536];   // 128 KB: 2 x {B 32KB, A 32KB}
  int t = threadIdx.x;
  int wid = t >> 6, l = t & 63;
  int wm = wid >> 2, wn = wid & 3;            // 2 x 4 waves; wave tile 128 x 64
  int lm = l & 15, g = l >> 4;

  int orig = blockIdx.x;                      // 256 wgs, 8 XCDs -> bijective
  int wg = ((orig & 7) << 5) | (orig >> 3);
  int bm0 = (wg >> 2) << 8, bn0 = (wg & 3) << 8;

  // staging source (pre-swizzled global col; LDS dest linear)
  int rowL = t >> 3;
  int colE = ((t & 7) ^ (rowL & 7)) << 3;
  const u16* pA = A + (size_t)(bm0 + ((rowL >> 5) << 7) + (rowL & 31)) * D_DIM + colE;
  const u16* pB = Bm + (size_t)(bn0 + rowL) * D_DIM + colE;
  u16* ldsW = lds + wid * 512;                // wave-uniform dst base

#define STAGE_B(tile, c) gload_lds16(pB + (size_t)(tile) * 64 + (size_t)(c) * 65536, \
                                     ldsW + ((tile) & 1) * 32768 + (c) * 4096)
#define STAGE_A(tile, q) gload_lds16(pA + (size_t)(tile) * 64 + (size_t)(q) * 32768, \
                                     ldsW + ((tile) & 1) * 32768 + 16384 + (q) * 4096)

  // read-side swizzled byte addresses
  unsigned lb = (unsigned)(uintptr_t)(const char*)lds;
  unsigned xc0 = (unsigned)((g * 16) ^ ((lm & 7) << 4));
  unsigned Bb0 = lb + wn * 8192 + lm * 128 + xc0;
  unsigned Bb1 = Bb0 ^ 64u;
  unsigned Ab0 = lb + 32768 + (wm * 32 + lm) * 128 + xc0;
  unsigned Ab1 = Ab0 ^ 64u;

  f32x4 acc[8][4];
#pragma unroll
  for (int mi = 0; mi < 8; mi++)
#pragma unroll
    for (int ni = 0; ni < 4; ni++) acc[mi][ni] = 0.0f;

  // prologue: tile0 (8) + tile1 B0-3,A0,A1 (6) = 14 in flight
#pragma unroll
  for (int c = 0; c < 4; c++) STAGE_B(0, c);
#pragma unroll
  for (int q = 0; q < 4; q++) STAGE_A(0, q);
#pragma unroll
  for (int c = 0; c < 4; c++) STAGE_B(1, c);
  STAGE_A(1, 0); STAGE_A(1, 1);
  asm volatile("s_waitcnt vmcnt(6)" ::: "memory");   // tile0 landed
  __builtin_amdgcn_s_barrier();

  bf16x8 bfr[4][2];
#pragma unroll 2
  for (int tt = 0; tt < NT; ++tt) {
    const unsigned cb = (unsigned)(tt & 1) * 65536u;
    // ---- phase 0: reads (B all + A q0) + stage, then barrier, then MFMA ----
#pragma unroll
    for (int ni = 0; ni < 4; ni++) {
      bfr[ni][0] = dsr128(Bb0 + cb + ni * 2048);
      bfr[ni][1] = dsr128(Bb1 + cb + ni * 2048);
    }
    bf16x8 a0[2][2];
#pragma unroll
    for (int s = 0; s < 2; s++) {
      a0[s][0] = dsr128(Ab0 + cb + s * 2048);
      a0[s][1] = dsr128(Ab1 + cb + s * 2048);
    }
    if (tt + 1 < NT) { STAGE_A(tt + 1, 2); STAGE_A(tt + 1, 3); }
    __builtin_amdgcn_s_barrier();
    asm volatile("s_waitcnt lgkmcnt(0)");
    __builtin_amdgcn_sched_barrier(0);
    __builtin_amdgcn_s_setprio(1);
#pragma unroll
    for (int ks = 0; ks < 2; ks++)
#pragma unroll
      for (int s = 0; s < 2; s++)
#pragma unroll
        for (int ni = 0; ni < 4; ni++)
          acc[s][ni] = __builtin_amdgcn_mfma_f32_16x16x32_bf16(a0[s][ks], bfr[ni][ks], acc[s][ni], 0, 0, 0);
    __builtin_amdgcn_s_setprio(0);
    __builtin_amdgcn_s_barrier();
    // ---- phases 1..3 ----
#pragma unroll
    for (int q = 1; q < 4; q++) {
      bf16x8 aq[2][2];
#pragma unroll
      for (int s = 0; s < 2; s++) {
        aq[s][0] = dsr128(Ab0 + cb + q * 8192 + s * 2048);
        aq[s][1] = dsr128(Ab1 + cb + q * 8192 + s * 2048);
      }
      if (tt + 2 < NT) {
        if (q == 1)      { STAGE_B(tt + 2, 0); STAGE_B(tt + 2, 1); }
        else if (q == 2) { STAGE_B(tt + 2, 2); STAGE_B(tt + 2, 3); }
        else             { STAGE_A(tt + 2, 0); STAGE_A(tt + 2, 1); }
      }
      __builtin_amdgcn_s_barrier();
      asm volatile("s_waitcnt lgkmcnt(0)");
      __builtin_amdgcn_sched_barrier(0);
      __builtin_amdgcn_s_setprio(1);
#pragma unroll
      for (int ks = 0; ks < 2; ks++)
#pragma unroll
        for (int s = 0; s < 2; s++)
#pragma unroll
          for (int ni = 0; ni < 4; ni++)
            acc[2 * q + s][ni] = __builtin_amdgcn_mfma_f32_16x16x32_bf16(aq[s][ks], bfr[ni][ks], acc[2 * q + s][ni], 0, 0, 0);
      __builtin_amdgcn_s_setprio(0);
      if (q == 3) {  // once per tile: next tile fully landed, keep tt+2's 6 in flight
        if (tt + 2 < NT)      asm volatile("s_waitcnt vmcnt(6)" ::: "memory");
        else if (tt + 1 < NT) asm volatile("s_waitcnt vmcnt(0)" ::: "memory");
      }
      __builtin_amdgcn_s_barrier();
    }
  }
#undef STAGE_A
#undef STAGE_B

  // ---- epilogue ----  m = bm0+wm*128+mi*16+g*4+j, n = bn0+wn*64+ni*16+lm
  int nidx[4]; float bia[4], dec[4];
#pragma unroll
  for (int ni = 0; ni < 4; ni++) {
    nidx[ni] = bn0 + wn * 64 + ni * 16 + lm;
    bia[ni] = bias[nidx[ni]];
    dec[ni] = (EPI == 0) ? decay[nidx[ni]] : 0.0f;
  }
#pragma unroll
  for (int mi = 0; mi < 8; mi++)
#pragma unroll
    for (int j = 0; j < 4; j++) {
      size_t m = (size_t)bm0 + wm * 128 + mi * 16 + g * 4 + j;
      if (EPI == 0) {
        const u16* xr = xfB + m * D_DIM;
        u16* orow = outB + m * D_DIM;
#pragma unroll
        for (int ni = 0; ni < 4; ni++) {
          float v = acc[mi][ni][j] + bia[ni];
          float gt = 1.0f / (1.0f + __expf(-v));
          orow[nidx[ni]] = f2b(gt * b2f(xr[nidx[ni]]) * dec[ni]);
        }
      } else if (EPI == 1) {
        const u16* xr = xfB + m * D_DIM;
        u16* orow = outB + m * D_DIM;
#pragma unroll
        for (int ni = 0; ni < 4; ni++)
          orow[nidx[ni]] = f2b(acc[mi][ni][j] + bia[ni] + b2f(xr[nidx[ni]]));
      } else {
        float p = probs[m * 4 + eIdx];
        float* orow = outF + m * D_DIM;
#pragma unroll
        for (int ni = 0; ni < 4; ni++) {
          float v = p * (acc[mi][ni][j] + bia[ni]);
          float prev = eIdx ? orow[nidx[ni]] : 0.0f;
          orow[nidx[ni]] = prev + v;
        }
      }
    }
}

// Row LayerNorm over D=1024 on bf16 input; writes bf16 (next A) and optionally f32.
template <int WF32>
__global__ __launch_bounds__(256) void ln_kernel(const u16* __restrict__ src,
                                                 const float* __restrict__ gamma,
                                                 const float* __restrict__ beta,
                                                 float* __restrict__ dstF, u16* __restrict__ dstB) {
  size_t row = blockIdx.x;
  int t = threadIdx.x, w = t >> 6, l = t & 63;
  u16x4 vb = ((const u16x4*)(src + row * D_DIM))[t];
  float v[4];
#pragma unroll
  for (int i = 0; i < 4; i++) v[i] = b2f(vb[i]);
  float s = v[0] + v[1] + v[2] + v[3];
  float q = v[0]*v[0] + v[1]*v[1] + v[2]*v[2] + v[3]*v[3];
#pragma unroll
  for (int off = 32; off; off >>= 1) { s += __shfl_xor(s, off); q += __shfl_xor(q, off); }
  __shared__ float red[8];
  if (l == 0) { red[w] = s; red[4 + w] = q; }
  __syncthreads();
  s = red[0] + red[1] + red[2] + red[3];
  q = red[4] + red[5] + red[6] + red[7];
  float mu = s * (1.0f / 1024.0f);
  float var = q * (1.0f / 1024.0f) - mu * mu;
  float inv = rsqrtf(var + 1e-5f);
  f32x4 gm = ((const f32x4*)gamma)[t], b = ((const f32x4*)beta)[t];
  f32x4 y; u16x4 yb;
#pragma unroll
  for (int i = 0; i < 4; i++) { y[i] = (v[i] - mu) * inv * gm[i] + b[i]; yb[i] = f2b(y[i]); }
  ((u16x4*)(dstB + row * D_DIM))[t] = yb;
  if (WF32) ((f32x4*)(dstF + row * D_DIM))[t] = y;
}

// f32 -> bf16 elementwise
__global__ void conv_kernel(const float* __restrict__ src, u16* __restrict__ dst, int n4) {
  int i = blockIdx.x * 256 + threadIdx.x;
  if (i >= n4) return;
  f32x4 v = ((const f32x4*)src)[i];
  u16x4 o;
#pragma unroll
  for (int j = 0; j < 4; j++) o[j] = f2b(v[j]);
  ((u16x4*)dst)[i] = o;
}

// Gate: logits + softmax -> probs[m,0..3]. One wave per row.
__global__ __launch_bounds__(256) void gate_kernel(const u16* __restrict__ zb,
                                                   const float* __restrict__ gW,
                                                   const float* __restrict__ gb,
                                                   float* __restrict__ probs) {
  __shared__ float sW[4096];
  int t = threadIdx.x;
#pragma unroll
  for (int c = 0; c < 4; c++) ((f32x4*)sW)[c * 256 + t] = ((const f32x4*)gW)[c * 256 + t];
  __syncthreads();
  int w = t >> 6, l = t & 63;
  size_t m = (size_t)blockIdx.x * 4 + w;
  const u16* zr = zb + m * D_DIM;
  float d0 = 0, d1 = 0, d2 = 0, d3 = 0;
#pragma unroll
  for (int c = 0; c < 4; c++) {
    int k = l * 4 + c * 256;
    u16x4 zv = *(const u16x4*)(zr + k);
    f32x4 w0 = *(const f32x4*)&sW[k];
    f32x4 w1 = *(const f32x4*)&sW[1024 + k];
    f32x4 w2 = *(const f32x4*)&sW[2048 + k];
    f32x4 w3 = *(const f32x4*)&sW[3072 + k];
#pragma unroll
    for (int i = 0; i < 4; i++) {
      float zf = b2f(zv[i]);
      d0 += zf * w0[i]; d1 += zf * w1[i]; d2 += zf * w2[i]; d3 += zf * w3[i];
    }
  }
#pragma unroll
  for (int off = 32; off; off >>= 1) {
    d0 += __shfl_xor(d0, off); d1 += __shfl_xor(d1, off);
    d2 += __shfl_xor(d2, off); d3 += __shfl_xor(d3, off);
  }
  if (l == 0) {
    float l0 = d0 + gb[0], l1 = d1 + gb[1], l2 = d2 + gb[2], l3 = d3 + gb[3];
    float mx = fmaxf(fmaxf(l0, l1), fmaxf(l2, l3));
    float e0 = __expf(l0 - mx), e1 = __expf(l1 - mx), e2 = __expf(l2 - mx), e3 = __expf(l3 - mx);
    float inv = 1.0f / (e0 + e1 + e2 + e3);
    f32x4 r; r[0] = e0 * inv; r[1] = e1 * inv; r[2] = e2 * inv; r[3] = e3 * inv;
    ((f32x4*)(probs + m * 4))[0] = r;
  }
}

extern "C" void kernel_launch(void* const* d_in, const int* in_sizes, int n_in,
                              void* d_out, int out_size, void* d_ws, size_t ws_size,
                              hipStream_t stream) {
  (void)in_sizes; (void)n_in; (void)out_size; (void)ws_size;
  const float* x_ctx    = (const float*)d_in[0];
  const float* x_tgt    = (const float*)d_in[1];
  const float* enc_Win  = (const float*)d_in[2];
  const float* enc_bin  = (const float*)d_in[3];
  const float* enc_dec  = (const float*)d_in[4];
  const float* enc_Wout = (const float*)d_in[5];
  const float* enc_bout = (const float*)d_in[6];
  const float* enc_gam  = (const float*)d_in[7];
  const float* enc_bet  = (const float*)d_in[8];
  const float* tgt_Win  = (const float*)d_in[9];
  const float* tgt_bin  = (const float*)d_in[10];
  const float* tgt_dec  = (const float*)d_in[11];
  const float* tgt_Wout = (const float*)d_in[12];
  const float* tgt_bout = (const float*)d_in[13];
  const float* tgt_gam  = (const float*)d_in[14];
  const float* tgt_bet  = (const float*)d_in[15];
  const float* gate_W   = (const float*)d_in[16];
  const float* gate_b   = (const float*)d_in[17];
  const float* exp_W    = (const float*)d_in[18];
  const float* exp_b    = (const float*)d_in[19];

  // d_out: pred_z[16M] | gate_probs[64K] | z_target[16M]
  float* out_pred  = (float*)d_out;
  float* out_probs = out_pred + (size_t)M_TOT * D_DIM;
  float* out_ztgt  = out_probs + (size_t)M_TOT * 4;

  // ws: bf16 weights (32MB) | xb(32MB) | sb(32MB) | ob(32MB)
  char* ws = (char*)d_ws;
  u16* wbEncIn  = (u16*)ws;
  u16* wbEncOut = wbEncIn  + (size_t)3 * 1048576;
  u16* wbTgtIn  = wbEncOut + (size_t)3 * 1048576;
  u16* wbTgtOut = wbTgtIn  + (size_t)3 * 1048576;
  u16* wbExp    = wbTgtOut + (size_t)3 * 1048576;
  u16* xb       = wbExp    + (size_t)4 * 1048576;
  u16* sb       = xb + (size_t)M_TOT * D_DIM;
  u16* ob       = sb + (size_t)M_TOT * D_DIM;

  auto conv = [&](const float* s, u16* d, size_t n) {
    int n4 = (int)(n / 4);
    conv_kernel<<<(n4 + 255) / 256, 256, 0, stream>>>(s, d, n4);
  };
  conv(enc_Win,  wbEncIn,  (size_t)3 * 1048576);
  conv(enc_Wout, wbEncOut, (size_t)3 * 1048576);
  conv(tgt_Win,  wbTgtIn,  (size_t)3 * 1048576);
  conv(tgt_Wout, wbTgtOut, (size_t)3 * 1048576);
  conv(exp_W,    wbExp,    (size_t)4 * 1048576);

  // ---- target stack ----
  conv(x_tgt, xb, (size_t)M_TOT * D_DIM);
  for (int i = 0; i < N_LAYERS; i++) {
    gemm8p<0><<<256, 512, 0, stream>>>(xb, wbTgtIn + (size_t)i * 1048576,
                                       tgt_bin + i * 1024, tgt_dec + i * 1024, xb,
                                       nullptr, 0, sb, nullptr);
    gemm8p<1><<<256, 512, 0, stream>>>(sb, wbTgtOut + (size_t)i * 1048576,
                                       tgt_bout + i * 1024, nullptr, xb,
                                       nullptr, 0, ob, nullptr);
    if (i == N_LAYERS - 1)
      ln_kernel<1><<<M_TOT, 256, 0, stream>>>(ob, tgt_gam + i * 1024, tgt_bet + i * 1024, out_ztgt, xb);
    else
      ln_kernel<0><<<M_TOT, 256, 0, stream>>>(ob, tgt_gam + i * 1024, tgt_bet + i * 1024, nullptr, xb);
  }

  // ---- context stack ----
  conv(x_ctx, xb, (size_t)M_TOT * D_DIM);
  for (int i = 0; i < N_LAYERS; i++) {
    gemm8p<0><<<256, 512, 0, stream>>>(xb, wbEncIn + (size_t)i * 1048576,
                                       enc_bin + i * 1024, enc_dec + i * 1024, xb,
                                       nullptr, 0, sb, nullptr);
    gemm8p<1><<<256, 512, 0, stream>>>(sb, wbEncOut + (size_t)i * 1048576,
                                       enc_bout + i * 1024, nullptr, xb,
                                       nullptr, 0, ob, nullptr);
    ln_kernel<0><<<M_TOT, 256, 0, stream>>>(ob, enc_gam + i * 1024, enc_bet + i * 1024, nullptr, xb);
  }

  // ---- MoE head ----
  gate_kernel<<<M_TOT / 4, 256, 0, stream>>>(xb, gate_W, gate_b, out_probs);
  for (int e = 0; e < 4; e++) {
    gemm8p<2><<<256, 512, 0, stream>>>(xb, wbExp + (size_t)e * 1048576,
                                       exp_b + e * 1024, nullptr, nullptr,
                                       out_probs, e, nullptr, out_pred);
  }
}

// Round 4
// 818.645 us; speedup vs baseline: 1.7472x; 1.0755x over previous
//
#include <hip/hip_runtime.h>
#include <stdint.h>

#define D_DIM 1024
#define M_TOT 16384   // 8 * 2048
#define N_LAYERS 3
#define NT 16         // K tiles (K=1024 / BK=64)

typedef unsigned short u16;
typedef __attribute__((ext_vector_type(8))) short bf16x8;
typedef __attribute__((ext_vector_type(4))) float f32x4;
typedef __attribute__((ext_vector_type(4))) unsigned short u16x4;

typedef __attribute__((address_space(1))) void gvoid_t;
typedef __attribute__((address_space(3))) void lvoid_t;

__device__ __forceinline__ float b2f(u16 u) {
  union { unsigned int i; float f; } x; x.i = ((unsigned int)u) << 16; return x.f;
}
__device__ __forceinline__ u16 f2b(float f) {  // RNE f32 -> bf16
  union { float f; unsigned int i; } x; x.f = f;
  unsigned int r = x.i + 0x7fffu + ((x.i >> 16) & 1u);
  return (u16)(r >> 16);
}

__device__ __forceinline__ void gload_lds16(const void* g, void* l) {
  __builtin_amdgcn_global_load_lds((gvoid_t*)(uintptr_t)g,
                                   (lvoid_t*)(unsigned int)(uintptr_t)l, 16, 0, 0);
}

// Opaque LDS read (compiler sees no LDS read -> no inserted waits on it).
// Ordering: explicit lgkmcnt(0) + sched_barrier(0) before MFMA (rule #18).
__device__ __forceinline__ bf16x8 dsr128(unsigned addr) {
  bf16x8 r;
  asm volatile("ds_read_b128 %0, %1" : "=v"(r) : "v"(addr));
  return r;
}

// ---------------------------------------------------------------------------
// 8-phase 256x256 GEMM engine, ONE barrier per phase.
// Hazard audit for single end-of-phase barrier (all stages write regions dead
// >= 1 barrier earlier; all waves' reads of a region complete before their
// own lgkmcnt(0)+MFMA, hence before they arrive at that phase's barrier):
//   p0 stages A(tt+1) chunks 2,3 -> buf cur^1, last read tile tt-1 phases 2,3 (>=1 BAR ago)
//   p1 stages B(tt+2) chunks 0,1 -> buf cur,   last read tile tt   phase 0    (1 BAR ago)
//   p2 stages B(tt+2) chunks 2,3 -> buf cur,   last read tile tt   phase 0    (2 BARs ago)
//   p3 stages A(tt+2) chunks 0,1 -> buf cur,   last read tile tt   phases 0,1 (>=2 BARs ago)
// Read-safety of staged data: vmcnt(6) at q3 (drains tile tt+1's 8 oldest
// loads, keeps tile tt+2's 6 in flight) + that phase's barrier.
// EPI 0: outB = bf16(sigmoid(acc+bias) * xb * decay)
// EPI 1: outB = bf16(acc + bias + xb)            (pre-LN)
// EPI 2: outB = bf16(p*(acc+bias))               (MoE e0)
// EPI 3: outB = bf16(outB + p*(acc+bias))        (MoE e1,e2; bf16 RMW)
// EPI 4: outF = outB + p*(acc+bias)              (MoE e3; final f32)
// ---------------------------------------------------------------------------
template <int EPI>
__global__ __launch_bounds__(512) void gemm8p(
    const u16* __restrict__ A, const u16* __restrict__ Bm,
    const float* __restrict__ bias, const float* __restrict__ decay,
    const u16* __restrict__ xfB, const float* __restrict__ probs, int eIdx,
    u16* __restrict__ outB, float* __restrict__ outF)
{
  __shared__ __align__(128) u16 lds[65536];   // 128 KB: 2 x {B 32KB, A 32KB}
  int t = threadIdx.x;
  int wid = t >> 6, l = t & 63;
  int wm = wid >> 2, wn = wid & 3;            // 2 x 4 waves; wave tile 128 x 64
  int lm = l & 15, g = l >> 4;

  int orig = blockIdx.x;                      // 256 wgs, 8 XCDs -> bijective
  int wg = ((orig & 7) << 5) | (orig >> 3);
  int bm0 = (wg >> 2) << 8, bn0 = (wg & 3) << 8;

  // staging source (pre-swizzled global col; LDS dest linear)
  int rowL = t >> 3;
  int colE = ((t & 7) ^ (rowL & 7)) << 3;
  const u16* pA = A + (size_t)(bm0 + ((rowL >> 5) << 7) + (rowL & 31)) * D_DIM + colE;
  const u16* pB = Bm + (size_t)(bn0 + rowL) * D_DIM + colE;
  u16* ldsW = lds + wid * 512;                // wave-uniform dst base

#define STAGE_B(tile, c) gload_lds16(pB + (size_t)(tile) * 64 + (size_t)(c) * 65536, \
                                     ldsW + ((tile) & 1) * 32768 + (c) * 4096)
#define STAGE_A(tile, q) gload_lds16(pA + (size_t)(tile) * 64 + (size_t)(q) * 32768, \
                                     ldsW + ((tile) & 1) * 32768 + 16384 + (q) * 4096)

  // read-side swizzled byte addresses
  unsigned lb = (unsigned)(uintptr_t)(const char*)lds;
  unsigned xc0 = (unsigned)((g * 16) ^ ((lm & 7) << 4));
  unsigned Bb0 = lb + wn * 8192 + lm * 128 + xc0;
  unsigned Bb1 = Bb0 ^ 64u;
  unsigned Ab0 = lb + 32768 + (wm * 32 + lm) * 128 + xc0;
  unsigned Ab1 = Ab0 ^ 64u;

  f32x4 acc[8][4];
#pragma unroll
  for (int mi = 0; mi < 8; mi++)
#pragma unroll
    for (int ni = 0; ni < 4; ni++) acc[mi][ni] = 0.0f;

  // prologue: tile0 (8) + tile1 B0-3,A0,A1 (6) = 14 in flight
#pragma unroll
  for (int c = 0; c < 4; c++) STAGE_B(0, c);
#pragma unroll
  for (int q = 0; q < 4; q++) STAGE_A(0, q);
#pragma unroll
  for (int c = 0; c < 4; c++) STAGE_B(1, c);
  STAGE_A(1, 0); STAGE_A(1, 1);
  asm volatile("s_waitcnt vmcnt(6)" ::: "memory");   // tile0 landed
  __builtin_amdgcn_s_barrier();

  bf16x8 bfr[4][2];
#pragma unroll 2
  for (int tt = 0; tt < NT; ++tt) {
    const unsigned cb = (unsigned)(tt & 1) * 65536u;
    // ---- phase 0: stage early, reads, own-lgkm wait, MFMA, barrier ----
    if (tt + 1 < NT) { STAGE_A(tt + 1, 2); STAGE_A(tt + 1, 3); }
#pragma unroll
    for (int ni = 0; ni < 4; ni++) {
      bfr[ni][0] = dsr128(Bb0 + cb + ni * 2048);
      bfr[ni][1] = dsr128(Bb1 + cb + ni * 2048);
    }
    bf16x8 a0[2][2];
#pragma unroll
    for (int s = 0; s < 2; s++) {
      a0[s][0] = dsr128(Ab0 + cb + s * 2048);
      a0[s][1] = dsr128(Ab1 + cb + s * 2048);
    }
    asm volatile("s_waitcnt lgkmcnt(0)");
    __builtin_amdgcn_sched_barrier(0);
    __builtin_amdgcn_s_setprio(1);
#pragma unroll
    for (int ks = 0; ks < 2; ks++)
#pragma unroll
      for (int s = 0; s < 2; s++)
#pragma unroll
        for (int ni = 0; ni < 4; ni++)
          acc[s][ni] = __builtin_amdgcn_mfma_f32_16x16x32_bf16(a0[s][ks], bfr[ni][ks], acc[s][ni], 0, 0, 0);
    __builtin_amdgcn_s_setprio(0);
    __builtin_amdgcn_s_barrier();
    // ---- phases 1..3 ----
#pragma unroll
    for (int q = 1; q < 4; q++) {
      if (tt + 2 < NT) {
        if (q == 1)      { STAGE_B(tt + 2, 0); STAGE_B(tt + 2, 1); }
        else if (q == 2) { STAGE_B(tt + 2, 2); STAGE_B(tt + 2, 3); }
        else             { STAGE_A(tt + 2, 0); STAGE_A(tt + 2, 1); }
      }
      bf16x8 aq[2][2];
#pragma unroll
      for (int s = 0; s < 2; s++) {
        aq[s][0] = dsr128(Ab0 + cb + q * 8192 + s * 2048);
        aq[s][1] = dsr128(Ab1 + cb + q * 8192 + s * 2048);
      }
      asm volatile("s_waitcnt lgkmcnt(0)");
      __builtin_amdgcn_sched_barrier(0);
      __builtin_amdgcn_s_setprio(1);
#pragma unroll
      for (int ks = 0; ks < 2; ks++)
#pragma unroll
        for (int s = 0; s < 2; s++)
#pragma unroll
          for (int ni = 0; ni < 4; ni++)
            acc[2 * q + s][ni] = __builtin_amdgcn_mfma_f32_16x16x32_bf16(aq[s][ks], bfr[ni][ks], acc[2 * q + s][ni], 0, 0, 0);
      __builtin_amdgcn_s_setprio(0);
      if (q == 3) {  // once per tile: drain tile tt+1's 8, keep tt+2's 6 in flight
        if (tt + 2 < NT)      asm volatile("s_waitcnt vmcnt(6)" ::: "memory");
        else if (tt + 1 < NT) asm volatile("s_waitcnt vmcnt(0)" ::: "memory");
      }
      __builtin_amdgcn_s_barrier();
    }
  }
#undef STAGE_A
#undef STAGE_B

  // ---- epilogue ----  m = bm0+wm*128+mi*16+g*4+j, n = bn0+wn*64+ni*16+lm
  int nidx[4]; float bia[4], dec[4];
#pragma unroll
  for (int ni = 0; ni < 4; ni++) {
    nidx[ni] = bn0 + wn * 64 + ni * 16 + lm;
    bia[ni] = bias[nidx[ni]];
    dec[ni] = (EPI == 0) ? decay[nidx[ni]] : 0.0f;
  }
#pragma unroll
  for (int mi = 0; mi < 8; mi++)
#pragma unroll
    for (int j = 0; j < 4; j++) {
      size_t m = (size_t)bm0 + wm * 128 + mi * 16 + g * 4 + j;
      if (EPI == 0) {
        const u16* xr = xfB + m * D_DIM;
        u16* orow = outB + m * D_DIM;
#pragma unroll
        for (int ni = 0; ni < 4; ni++) {
          float v = acc[mi][ni][j] + bia[ni];
          float gt = 1.0f / (1.0f + __expf(-v));
          orow[nidx[ni]] = f2b(gt * b2f(xr[nidx[ni]]) * dec[ni]);
        }
      } else if (EPI == 1) {
        const u16* xr = xfB + m * D_DIM;
        u16* orow = outB + m * D_DIM;
#pragma unroll
        for (int ni = 0; ni < 4; ni++)
          orow[nidx[ni]] = f2b(acc[mi][ni][j] + bia[ni] + b2f(xr[nidx[ni]]));
      } else if (EPI == 2) {
        float p = probs[m * 4 + eIdx];
        u16* orow = outB + m * D_DIM;
#pragma unroll
        for (int ni = 0; ni < 4; ni++)
          orow[nidx[ni]] = f2b(p * (acc[mi][ni][j] + bia[ni]));
      } else if (EPI == 3) {
        float p = probs[m * 4 + eIdx];
        u16* orow = outB + m * D_DIM;
#pragma unroll
        for (int ni = 0; ni < 4; ni++)
          orow[nidx[ni]] = f2b(b2f(orow[nidx[ni]]) + p * (acc[mi][ni][j] + bia[ni]));
      } else {
        float p = probs[m * 4 + eIdx];
        const u16* srow = outB + m * D_DIM;
        float* orow = outF + m * D_DIM;
#pragma unroll
        for (int ni = 0; ni < 4; ni++)
          orow[nidx[ni]] = b2f(srow[nidx[ni]]) + p * (acc[mi][ni][j] + bia[ni]);
      }
    }
}

// Row LayerNorm over D=1024 on bf16 input; writes bf16 (next A) and optionally f32.
template <int WF32>
__global__ __launch_bounds__(256) void ln_kernel(const u16* __restrict__ src,
                                                 const float* __restrict__ gamma,
                                                 const float* __restrict__ beta,
                                                 float* __restrict__ dstF, u16* __restrict__ dstB) {
  size_t row = blockIdx.x;
  int t = threadIdx.x, w = t >> 6, l = t & 63;
  u16x4 vb = ((const u16x4*)(src + row * D_DIM))[t];
  float v[4];
#pragma unroll
  for (int i = 0; i < 4; i++) v[i] = b2f(vb[i]);
  float s = v[0] + v[1] + v[2] + v[3];
  float q = v[0]*v[0] + v[1]*v[1] + v[2]*v[2] + v[3]*v[3];
#pragma unroll
  for (int off = 32; off; off >>= 1) { s += __shfl_xor(s, off); q += __shfl_xor(q, off); }
  __shared__ float red[8];
  if (l == 0) { red[w] = s; red[4 + w] = q; }
  __syncthreads();
  s = red[0] + red[1] + red[2] + red[3];
  q = red[4] + red[5] + red[6] + red[7];
  float mu = s * (1.0f / 1024.0f);
  float var = q * (1.0f / 1024.0f) - mu * mu;
  float inv = rsqrtf(var + 1e-5f);
  f32x4 gm = ((const f32x4*)gamma)[t], b = ((const f32x4*)beta)[t];
  f32x4 y; u16x4 yb;
#pragma unroll
  for (int i = 0; i < 4; i++) { y[i] = (v[i] - mu) * inv * gm[i] + b[i]; yb[i] = f2b(y[i]); }
  ((u16x4*)(dstB + row * D_DIM))[t] = yb;
  if (WF32) ((f32x4*)(dstF + row * D_DIM))[t] = y;
}

// f32 -> bf16 elementwise
__global__ void conv_kernel(const float* __restrict__ src, u16* __restrict__ dst, int n4) {
  int i = blockIdx.x * 256 + threadIdx.x;
  if (i >= n4) return;
  f32x4 v = ((const f32x4*)src)[i];
  u16x4 o;
#pragma unroll
  for (int j = 0; j < 4; j++) o[j] = f2b(v[j]);
  ((u16x4*)dst)[i] = o;
}

// Gate: logits + softmax -> probs[m,0..3]. One wave per row.
__global__ __launch_bounds__(256) void gate_kernel(const u16* __restrict__ zb,
                                                   const float* __restrict__ gW,
                                                   const float* __restrict__ gb,
                                                   float* __restrict__ probs) {
  __shared__ float sW[4096];
  int t = threadIdx.x;
#pragma unroll
  for (int c = 0; c < 4; c++) ((f32x4*)sW)[c * 256 + t] = ((const f32x4*)gW)[c * 256 + t];
  __syncthreads();
  int w = t >> 6, l = t & 63;
  size_t m = (size_t)blockIdx.x * 4 + w;
  const u16* zr = zb + m * D_DIM;
  float d0 = 0, d1 = 0, d2 = 0, d3 = 0;
#pragma unroll
  for (int c = 0; c < 4; c++) {
    int k = l * 4 + c * 256;
    u16x4 zv = *(const u16x4*)(zr + k);
    f32x4 w0 = *(const f32x4*)&sW[k];
    f32x4 w1 = *(const f32x4*)&sW[1024 + k];
    f32x4 w2 = *(const f32x4*)&sW[2048 + k];
    f32x4 w3 = *(const f32x4*)&sW[3072 + k];
#pragma unroll
    for (int i = 0; i < 4; i++) {
      float zf = b2f(zv[i]);
      d0 += zf * w0[i]; d1 += zf * w1[i]; d2 += zf * w2[i]; d3 += zf * w3[i];
    }
  }
#pragma unroll
  for (int off = 32; off; off >>= 1) {
    d0 += __shfl_xor(d0, off); d1 += __shfl_xor(d1, off);
    d2 += __shfl_xor(d2, off); d3 += __shfl_xor(d3, off);
  }
  if (l == 0) {
    float l0 = d0 + gb[0], l1 = d1 + gb[1], l2 = d2 + gb[2], l3 = d3 + gb[3];
    float mx = fmaxf(fmaxf(l0, l1), fmaxf(l2, l3));
    float e0 = __expf(l0 - mx), e1 = __expf(l1 - mx), e2 = __expf(l2 - mx), e3 = __expf(l3 - mx);
    float inv = 1.0f / (e0 + e1 + e2 + e3);
    f32x4 r; r[0] = e0 * inv; r[1] = e1 * inv; r[2] = e2 * inv; r[3] = e3 * inv;
    ((f32x4*)(probs + m * 4))[0] = r;
  }
}

extern "C" void kernel_launch(void* const* d_in, const int* in_sizes, int n_in,
                              void* d_out, int out_size, void* d_ws, size_t ws_size,
                              hipStream_t stream) {
  (void)in_sizes; (void)n_in; (void)out_size; (void)ws_size;
  const float* x_ctx    = (const float*)d_in[0];
  const float* x_tgt    = (const float*)d_in[1];
  const float* enc_Win  = (const float*)d_in[2];
  const float* enc_bin  = (const float*)d_in[3];
  const float* enc_dec  = (const float*)d_in[4];
  const float* enc_Wout = (const float*)d_in[5];
  const float* enc_bout = (const float*)d_in[6];
  const float* enc_gam  = (const float*)d_in[7];
  const float* enc_bet  = (const float*)d_in[8];
  const float* tgt_Win  = (const float*)d_in[9];
  const float* tgt_bin  = (const float*)d_in[10];
  const float* tgt_dec  = (const float*)d_in[11];
  const float* tgt_Wout = (const float*)d_in[12];
  const float* tgt_bout = (const float*)d_in[13];
  const float* tgt_gam  = (const float*)d_in[14];
  const float* tgt_bet  = (const float*)d_in[15];
  const float* gate_W   = (const float*)d_in[16];
  const float* gate_b   = (const float*)d_in[17];
  const float* exp_W    = (const float*)d_in[18];
  const float* exp_b    = (const float*)d_in[19];

  // d_out: pred_z[16M] | gate_probs[64K] | z_target[16M]
  float* out_pred  = (float*)d_out;
  float* out_probs = out_pred + (size_t)M_TOT * D_DIM;
  float* out_ztgt  = out_probs + (size_t)M_TOT * 4;

  // ws: bf16 weights (32MB) | xb(32MB) | sb(32MB) | ob(32MB)
  char* ws = (char*)d_ws;
  u16* wbEncIn  = (u16*)ws;
  u16* wbEncOut = wbEncIn  + (size_t)3 * 1048576;
  u16* wbTgtIn  = wbEncOut + (size_t)3 * 1048576;
  u16* wbTgtOut = wbTgtIn  + (size_t)3 * 1048576;
  u16* wbExp    = wbTgtOut + (size_t)3 * 1048576;
  u16* xb       = wbExp    + (size_t)4 * 1048576;
  u16* sb       = xb + (size_t)M_TOT * D_DIM;
  u16* ob       = sb + (size_t)M_TOT * D_DIM;

  auto conv = [&](const float* s, u16* d, size_t n) {
    int n4 = (int)(n / 4);
    conv_kernel<<<(n4 + 255) / 256, 256, 0, stream>>>(s, d, n4);
  };
  conv(enc_Win,  wbEncIn,  (size_t)3 * 1048576);
  conv(enc_Wout, wbEncOut, (size_t)3 * 1048576);
  conv(tgt_Win,  wbTgtIn,  (size_t)3 * 1048576);
  conv(tgt_Wout, wbTgtOut, (size_t)3 * 1048576);
  conv(exp_W,    wbExp,    (size_t)4 * 1048576);

  // ---- target stack ----
  conv(x_tgt, xb, (size_t)M_TOT * D_DIM);
  for (int i = 0; i < N_LAYERS; i++) {
    gemm8p<0><<<256, 512, 0, stream>>>(xb, wbTgtIn + (size_t)i * 1048576,
                                       tgt_bin + i * 1024, tgt_dec + i * 1024, xb,
                                       nullptr, 0, sb, nullptr);
    gemm8p<1><<<256, 512, 0, stream>>>(sb, wbTgtOut + (size_t)i * 1048576,
                                       tgt_bout + i * 1024, nullptr, xb,
                                       nullptr, 0, ob, nullptr);
    if (i == N_LAYERS - 1)
      ln_kernel<1><<<M_TOT, 256, 0, stream>>>(ob, tgt_gam + i * 1024, tgt_bet + i * 1024, out_ztgt, xb);
    else
      ln_kernel<0><<<M_TOT, 256, 0, stream>>>(ob, tgt_gam + i * 1024, tgt_bet + i * 1024, nullptr, xb);
  }

  // ---- context stack ----
  conv(x_ctx, xb, (size_t)M_TOT * D_DIM);
  for (int i = 0; i < N_LAYERS; i++) {
    gemm8p<0><<<256, 512, 0, stream>>>(xb, wbEncIn + (size_t)i * 1048576,
                                       enc_bin + i * 1024, enc_dec + i * 1024, xb,
                                       nullptr, 0, sb, nullptr);
    gemm8p<1><<<256, 512, 0, stream>>>(sb, wbEncOut + (size_t)i * 1048576,
                                       enc_bout + i * 1024, nullptr, xb,
                                       nullptr, 0, ob, nullptr);
    ln_kernel<0><<<M_TOT, 256, 0, stream>>>(ob, enc_gam + i * 1024, enc_bet + i * 1024, nullptr, xb);
  }

  // ---- MoE head: gate probs, then 4 passes; bf16 running sum in sb ----
  gate_kernel<<<M_TOT / 4, 256, 0, stream>>>(xb, gate_W, gate_b, out_probs);
  gemm8p<2><<<256, 512, 0, stream>>>(xb, wbExp,               exp_b,        nullptr, nullptr,
                                     out_probs, 0, sb, nullptr);
  gemm8p<3><<<256, 512, 0, stream>>>(xb, wbExp + 1048576,     exp_b + 1024, nullptr, nullptr,
                                     out_probs, 1, sb, nullptr);
  gemm8p<3><<<256, 512, 0, stream>>>(xb, wbExp + 2 * 1048576, exp_b + 2048, nullptr, nullptr,
                                     out_probs, 2, sb, nullptr);
  gemm8p<4><<<256, 512, 0, stream>>>(xb, wbExp + 3 * 1048576, exp_b + 3072, nullptr, nullptr,
                                     out_probs, 3, sb, out_pred);
}